// Round 6
// baseline (1027.276 us; speedup 1.0000x reference)
//
#include <hip/hip_runtime.h>
#include <hip/hip_bf16.h>

#define B_SZ 100000
#define NTOT 200000
#define NN   1000000
#define DIM  128

#define NB_CLAIM  782               // ceil(2e5/256)
#define NB_WFRAG  32
#define NB_PREP   (NB_CLAIM + NB_WFRAG + 1)

#define SUPER     32                // nodes per wave supertile
#define NSUP      31250             // 1e6 / 32
#define GRID_MAIN 512               // 2 blocks/CU (65 KB LDS each)
#define BLK_MAIN  512               // 8 waves
#define NWAVE     (GRID_MAIN * 8)   // 4096 wave slots

typedef short bf16x8 __attribute__((ext_vector_type(8)));
typedef float f32x4  __attribute__((ext_vector_type(4)));

__device__ __forceinline__ short f2bf(float f) {
    union { float f; unsigned u; } v; v.f = f;
    unsigned u = v.u;
    u += 0x7fffu + ((u >> 16) & 1u);
    return (short)(u >> 16);
}

__device__ __forceinline__ bf16x8 cvt8(f32x4 a, f32x4 b) {
    bf16x8 r;
    r[0]=f2bf(a[0]); r[1]=f2bf(a[1]); r[2]=f2bf(a[2]); r[3]=f2bf(a[3]);
    r[4]=f2bf(b[0]); r[5]=f2bf(b[1]); r[6]=f2bf(b[2]); r[7]=f2bf(b[3]);
    return r;
}

// ---------------- launch 2: claim || weight packing || bias ----------------
//  owner[node] = max(code): src codes [0,B), dst [B,2B) -> dst beats src,
//  later index beats earlier -> numpy sequential scatter semantics.
//  PA[k][n] = W_node[n][k] + (k==n)            (applied to prev)
//  PQ[k][n] = sum_m W_node[n][m]*W_nig[m][k]   (applied to nbr)
//  cvec[n]  = b_node[n] + sum_k b_nig[k]*W_node[n][k]
// B-frag layout (16x16x32 bf16): frag (kc,nc), lane l holds
//   col n = nc*16 + (l&15), k = kc*32 + (l>>4)*8 + i, i=0..7
__global__ __launch_bounds__(256) void k_prep(
        const int* __restrict__ src, const int* __restrict__ dst,
        int* __restrict__ owner,
        const float* __restrict__ Wnig, const float* __restrict__ bnig,
        const float* __restrict__ Wnode, const float* __restrict__ bnode,
        short* __restrict__ PA, short* __restrict__ PQ,
        float* __restrict__ cvec) {
    int b = blockIdx.x, t = threadIdx.x;
    if (b < NB_CLAIM) {
        int i = b * 256 + t;
        if (i < NTOT) {
            int node = (i < B_SZ) ? src[i] : dst[i - B_SZ];
            atomicMax(&owner[node], i);
        }
    } else if (b < NB_CLAIM + NB_WFRAG) {
        int b2 = b - NB_CLAIM;             // fragment index kc*8+nc
        int lane = t & 63, ig = t >> 6;    // ig 0..3 -> i = 2*ig, 2*ig+1
        int kc = b2 >> 3, nc = b2 & 7;
        int n = nc * 16 + (lane & 15);
        int kbase = kc * 32 + (lane >> 4) * 8;
        int fo = (b2 * 64 + lane) * 8;
        for (int ii = 0; ii < 2; ++ii) {
            int i = ig * 2 + ii;
            int k = kbase + i;
            float a = Wnode[n * DIM + k] + (k == n ? 1.0f : 0.0f);
            PA[fo + i] = f2bf(a);
            float q = 0.f;
            for (int m = 0; m < DIM; ++m) q += Wnode[n * DIM + m] * Wnig[m * DIM + k];
            PQ[fo + i] = f2bf(q);
        }
    } else {
        if (t < DIM) {
            float c = bnode[t];
            for (int k = 0; k < DIM; ++k) c += bnig[k] * Wnode[t * DIM + k];
            cvec[t] = c;
        }
    }
}

// ---------------- launch 3: supertile copy + compacted MFMA update ----------
// Per wave per 32-node supertile:
//   1. owner ballot -> mask, compact touched rows into LDS list (rank by popc)
//   2. coalesced linear copy of all 32 rows (stores masked for touched rows)
//   3. one (rarely two) 16-row MFMA tile over COMPACTED touched rows only;
//      A-prev re-read gathered from L2 (hot from step 2), nbr gathered masked
__global__ __launch_bounds__(BLK_MAIN, 4) void k_node(
        const float* __restrict__ prev,
        const float* __restrict__ nsrc, const float* __restrict__ ndst,
        const int* __restrict__ owner,
        const short* __restrict__ PA, const short* __restrict__ PQ,
        const float* __restrict__ cvec,
        float* __restrict__ out) {
    __shared__ __align__(16) short lA[32 * 64 * 8];   // 32 KB
    __shared__ __align__(16) short lQ[32 * 64 * 8];   // 32 KB
    __shared__ int lists[8][SUPER];                   // 1 KB
    int tid = threadIdx.x;
    {
        const float4* gA = (const float4*)PA;
        const float4* gQ = (const float4*)PQ;
        float4* sA = (float4*)lA;
        float4* sQ = (float4*)lQ;
        for (int i = tid; i < 2048; i += BLK_MAIN) { sA[i] = gA[i]; sQ[i] = gQ[i]; }
    }
    __syncthreads();

    int wave = tid >> 6, lane = tid & 63;
    int* list = lists[wave];
    int koff  = (lane >> 4) * 8;    // float offset within row (A/B frag)
    int col0  = lane & 15;          // D-frag col
    int rbase = (lane >> 4) * 4;    // D-frag row base

    float cv[8];
#pragma unroll
    for (int nc = 0; nc < 8; ++nc) cv[nc] = cvec[nc * 16 + col0];

    const f32x4 z = (f32x4){0.f, 0.f, 0.f, 0.f};

    for (int s = blockIdx.x * 8 + wave; s < NSUP; s += NWAVE) {
        size_t nbase = (size_t)s * SUPER;

        // --- ownership + compaction ---
        int own = -1;
        if (lane < SUPER) own = owner[nbase + lane];
        unsigned mask = (unsigned)__ballot(own >= 0);   // bits 0..31
        int cnt = __popc(mask);
        if (own >= 0) {
            int rank = __popc(mask & ((1u << lane) - 1u));
            list[rank] = (own << 5) | lane;             // code*32 | row
        }

        // --- coalesced copy of 32 rows (1024 float4), touched stores masked ---
        const f32x4* p4 = (const f32x4*)(prev + nbase * DIM);
        f32x4*       o4 = (f32x4*)(out  + nbase * DIM);
#pragma unroll
        for (int half = 0; half < 2; ++half) {
            f32x4 v[8];
#pragma unroll
            for (int j = 0; j < 8; ++j) v[j] = p4[(half * 8 + j) * 64 + lane];
#pragma unroll
            for (int j = 0; j < 8; ++j) {
                int fi = (half * 8 + j) * 64 + lane;
                int row = fi >> 5;                      // 32 f4 per row
                if (!((mask >> row) & 1u)) o4[fi] = v[j];
            }
        }

        if (cnt == 0) continue;

        const float* ps = prev + nbase * DIM;
        // --- MFMA over compacted rows: usually one tile (cnt<=16 w.p. ~1) ---
#pragma unroll 1
        for (int tb = 0; tb < SUPER; tb += 16) {
            if (cnt <= tb) break;
            int idx = tb + (lane & 15);
            bool act = idx < cnt;
            int pk = act ? list[idx] : 0;
            int arow = pk & 31;
            int code = pk >> 5;

            // nbr gather up front (long latency, masked)
            f32x4 nb[8];
#pragma unroll
            for (int i = 0; i < 8; ++i) nb[i] = z;
            if (act) {
                const float* nrow = (code < B_SZ
                        ? nsrc + (size_t)code * DIM
                        : ndst + (size_t)(code - B_SZ) * DIM) + koff;
#pragma unroll
                for (int kc = 0; kc < 4; ++kc) {
                    nb[2*kc]   = *(const f32x4*)(nrow + kc * 32);
                    nb[2*kc+1] = *(const f32x4*)(nrow + kc * 32 + 4);
                }
            }

            f32x4 acc[8];
#pragma unroll
            for (int nc = 0; nc < 8; ++nc) acc[nc] = z;

            const float* prow = ps + (size_t)arow * DIM + koff;
#pragma unroll
            for (int kc = 0; kc < 4; ++kc) {
                f32x4 a0 = z, a1 = z;
                if (act) {                              // L2-hot re-read
                    a0 = *(const f32x4*)(prow + kc * 32);
                    a1 = *(const f32x4*)(prow + kc * 32 + 4);
                }
                bf16x8 aP = cvt8(a0, a1);
                bf16x8 aN = cvt8(nb[2*kc], nb[2*kc+1]);
#pragma unroll
                for (int nc = 0; nc < 8; ++nc) {
                    int fo = ((kc * 8 + nc) * 64 + lane) * 8;
                    bf16x8 bA = *(const bf16x8*)(lA + fo);
                    bf16x8 bQ = *(const bf16x8*)(lQ + fo);
                    acc[nc] = __builtin_amdgcn_mfma_f32_16x16x32_bf16(aP, bA, acc[nc], 0, 0, 0);
                    acc[nc] = __builtin_amdgcn_mfma_f32_16x16x32_bf16(aN, bQ, acc[nc], 0, 0, 0);
                }
            }

            // epilogue: D row = compacted idx (col = l&15, row = (l>>4)*4 + r)
#pragma unroll
            for (int r = 0; r < 4; ++r) {
                int i2 = tb + rbase + r;
                if (i2 < cnt) {
                    int row2 = list[i2] & 31;
                    float* ow = out + (nbase + row2) * DIM;
#pragma unroll
                    for (int nc = 0; nc < 8; ++nc)
                        ow[nc * 16 + col0] = acc[nc][r] + cv[nc];
                }
            }
        }
    }
}

extern "C" void kernel_launch(void* const* d_in, const int* in_sizes, int n_in,
                              void* d_out, int out_size, void* d_ws, size_t ws_size,
                              hipStream_t stream) {
    const int*   src  = (const int*)d_in[0];
    const int*   dst  = (const int*)d_in[1];
    const float* prev = (const float*)d_in[2];
    const float* nsrc = (const float*)d_in[3];
    const float* ndst = (const float*)d_in[4];
    const float* Wnig = (const float*)d_in[5];
    const float* bnig = (const float*)d_in[6];
    const float* Wnode = (const float*)d_in[7];
    const float* bnode = (const float*)d_in[8];
    float* out = (float*)d_out;

    const size_t OWNER_B = (size_t)NN * 4;
    const size_t PA_B = 32 * 64 * 8 * 2;     // 32 KB each
    if (ws_size < OWNER_B + 2 * PA_B + 512) return;
    char* ws = (char*)d_ws;
    int*   owner = (int*)ws;
    short* PA = (short*)(ws + OWNER_B);
    short* PQ = (short*)(ws + OWNER_B + PA_B);
    float* cvec = (float*)(ws + OWNER_B + 2 * PA_B);

    hipMemsetAsync(owner, 0xFF, OWNER_B, stream);     // owner[i] = -1
    k_prep<<<NB_PREP, 256, 0, stream>>>(
        src, dst, owner, Wnig, bnig, Wnode, bnode, PA, PQ, cvec);
    k_node<<<GRID_MAIN, BLK_MAIN, 0, stream>>>(
        prev, nsrc, ndst, owner, PA, PQ, cvec, out);
}

// Round 7
// 255.434 us; speedup vs baseline: 4.0217x; 4.0217x over previous
//
#include <hip/hip_runtime.h>
#include <hip/hip_bf16.h>

#define B_SZ 100000
#define NTOT 200000
#define NN   1000000
#define DIM  128

#define NB_CLAIM  782               // ceil(2e5/256)
#define NB_WFRAG  32
#define NB_PREP   (NB_CLAIM + NB_WFRAG + 1)

#define TILES     62500             // 1e6 nodes / 16 per wave-tile
#define GRID_MAIN 512               // 2 blocks/CU (64 KB LDS each)
#define BLK_MAIN  512               // 8 waves
#define WAVES_TOT (GRID_MAIN * 8)   // 4096 wave slots

typedef short bf16x8 __attribute__((ext_vector_type(8)));
typedef float f32x4  __attribute__((ext_vector_type(4)));

__device__ __forceinline__ short f2bf(float f) {
    union { float f; unsigned u; } v; v.f = f;
    unsigned u = v.u;
    u += 0x7fffu + ((u >> 16) & 1u);
    return (short)(u >> 16);
}

// ---------------- launch 2: claim || weight packing || bias ----------------
//  owner[node] = max(code): src codes [0,B), dst [B,2B) -> dst beats src,
//  later index beats earlier -> numpy sequential scatter semantics.
//  PA[k][n] = W_node[n][k] + (k==n)            (applied to prev)
//  PQ[k][n] = sum_m W_node[n][m]*W_nig[m][k]   (applied to nbr)
//  cvec[n]  = b_node[n] + sum_k b_nig[k]*W_node[n][k]
// B-frag layout (16x16x32 bf16): frag (kc,nc), lane l holds
//   col n = nc*16 + (l&15), k = kc*32 + (l>>4)*8 + i, i=0..7
__global__ __launch_bounds__(256) void k_prep(
        const int* __restrict__ src, const int* __restrict__ dst,
        int* __restrict__ owner,
        const float* __restrict__ Wnig, const float* __restrict__ bnig,
        const float* __restrict__ Wnode, const float* __restrict__ bnode,
        short* __restrict__ PA, short* __restrict__ PQ,
        float* __restrict__ cvec) {
    int b = blockIdx.x, t = threadIdx.x;
    if (b < NB_CLAIM) {
        int i = b * 256 + t;
        if (i < NTOT) {
            int node = (i < B_SZ) ? src[i] : dst[i - B_SZ];
            atomicMax(&owner[node], i);
        }
    } else if (b < NB_CLAIM + NB_WFRAG) {
        int b2 = b - NB_CLAIM;             // fragment index kc*8+nc
        int lane = t & 63, ig = t >> 6;    // ig 0..3 -> i = 2*ig, 2*ig+1
        int kc = b2 >> 3, nc = b2 & 7;
        int n = nc * 16 + (lane & 15);
        int kbase = kc * 32 + (lane >> 4) * 8;
        int fo = (b2 * 64 + lane) * 8;
        for (int ii = 0; ii < 2; ++ii) {
            int i = ig * 2 + ii;
            int k = kbase + i;
            float a = Wnode[n * DIM + k] + (k == n ? 1.0f : 0.0f);
            PA[fo + i] = f2bf(a);
            float q = 0.f;
            for (int m = 0; m < DIM; ++m) q += Wnode[n * DIM + m] * Wnig[m * DIM + k];
            PQ[fo + i] = f2bf(q);
        }
    } else {
        if (t < DIM) {
            float c = bnode[t];
            for (int k = 0; k < DIM; ++k) c += bnig[k] * Wnode[t * DIM + k];
            cvec[t] = c;
        }
    }
}

// ---------------- launch 3: node-ordered fused update+copy (v1 + prefetch) --
// v1 structure (benched 252.7 us): conditional per-lane loads, um-loop copy,
// ~76 VGPR no spill. Only change: owner loaded one tile ahead (1 reg).
__global__ __launch_bounds__(BLK_MAIN, 4) void k_node(
        const float* __restrict__ prev,
        const float* __restrict__ nsrc, const float* __restrict__ ndst,
        const int* __restrict__ owner,
        const short* __restrict__ PA, const short* __restrict__ PQ,
        const float* __restrict__ cvec,
        float* __restrict__ out) {
    __shared__ __align__(16) short lA[32 * 64 * 8];   // 32 KB
    __shared__ __align__(16) short lQ[32 * 64 * 8];   // 32 KB
    int tid = threadIdx.x;
    {
        const float4* gA = (const float4*)PA;
        const float4* gQ = (const float4*)PQ;
        float4* sA = (float4*)lA;
        float4* sQ = (float4*)lQ;
        for (int i = tid; i < 2048; i += BLK_MAIN) { sA[i] = gA[i]; sQ[i] = gQ[i]; }
    }
    __syncthreads();

    int wave = tid >> 6, lane = tid & 63;
    int wid = blockIdx.x * 8 + wave;
    int myrow = lane & 15;
    int koff = (lane >> 4) * 8;
    int col0 = lane & 15;
    int rbase = (lane >> 4) * 4;

    // bias slice: constant per lane across tiles
    float cv[8];
#pragma unroll
    for (int nc = 0; nc < 8; ++nc) cv[nc] = cvec[nc * 16 + col0];

    int t = wid;
    if (t >= TILES) return;
    int o_cur = owner[t * 16 + myrow];          // prologue owner fetch

    for (; t < TILES; t += WAVES_TOT) {
        int tn = t + WAVES_TOT;
        int o_nxt = (tn < TILES) ? owner[tn * 16 + myrow] : -1;  // prefetch

        int nbase = t * 16;
        int my_owner = o_cur;
        unsigned mask16 = (unsigned)(__ballot(my_owner >= 0) & 0xFFFFu);

        if (mask16) {
            const float* prow = prev + (size_t)(nbase + myrow) * DIM;
            const float* nrow = prow;  // dummy init
            if (my_owner >= 0) {
                bool is_src = my_owner < B_SZ;
                int bi = is_src ? my_owner : my_owner - B_SZ;
                nrow = (is_src ? nsrc : ndst) + (size_t)bi * DIM;
            }
            f32x4 acc[8];
#pragma unroll
            for (int nc = 0; nc < 8; ++nc) acc[nc] = (f32x4){0.f, 0.f, 0.f, 0.f};

#pragma unroll
            for (int kc = 0; kc < 4; ++kc) {
                int k0 = kc * 32 + koff;
                bf16x8 aP = (bf16x8){0,0,0,0,0,0,0,0};
                bf16x8 aN = (bf16x8){0,0,0,0,0,0,0,0};
                if (my_owner >= 0) {
                    float4 p0 = *(const float4*)(prow + k0);
                    float4 p1 = *(const float4*)(prow + k0 + 4);
                    float4 n0 = *(const float4*)(nrow + k0);
                    float4 n1 = *(const float4*)(nrow + k0 + 4);
                    aP[0]=f2bf(p0.x); aP[1]=f2bf(p0.y); aP[2]=f2bf(p0.z); aP[3]=f2bf(p0.w);
                    aP[4]=f2bf(p1.x); aP[5]=f2bf(p1.y); aP[6]=f2bf(p1.z); aP[7]=f2bf(p1.w);
                    aN[0]=f2bf(n0.x); aN[1]=f2bf(n0.y); aN[2]=f2bf(n0.z); aN[3]=f2bf(n0.w);
                    aN[4]=f2bf(n1.x); aN[5]=f2bf(n1.y); aN[6]=f2bf(n1.z); aN[7]=f2bf(n1.w);
                }
#pragma unroll
                for (int nc = 0; nc < 8; ++nc) {
                    int fo = ((kc * 8 + nc) * 64 + lane) * 8;
                    bf16x8 bA = *(const bf16x8*)(lA + fo);
                    bf16x8 bQ = *(const bf16x8*)(lQ + fo);
                    acc[nc] = __builtin_amdgcn_mfma_f32_16x16x32_bf16(aP, bA, acc[nc], 0, 0, 0);
                    acc[nc] = __builtin_amdgcn_mfma_f32_16x16x32_bf16(aN, bQ, acc[nc], 0, 0, 0);
                }
            }
            // epilogue: touched rows from acc (D: col = l&15, row = (l>>4)*4 + r)
#pragma unroll
            for (int r = 0; r < 4; ++r) {
                int rt = rbase + r;
                if ((mask16 >> rt) & 1u) {
                    float* orow = out + (size_t)(nbase + rt) * DIM;
#pragma unroll
                    for (int nc = 0; nc < 8; ++nc)
                        orow[nc * 16 + col0] = acc[nc][r] + cv[nc];
                }
            }
        }

        // untouched rows: coalesced copy, two rows per iteration (1 KB/instr)
        unsigned um = (~mask16) & 0xFFFFu;
        while (um) {
            int r0 = __builtin_ctz(um); um &= um - 1;
            int r1 = -1;
            if (um) { r1 = __builtin_ctz(um); um &= um - 1; }
            int r = (lane < 32) ? r0 : r1;
            if (r >= 0) {
                const float4* s4 = (const float4*)(prev + (size_t)(nbase + r) * DIM);
                float4* d4 = (float4*)(out + (size_t)(nbase + r) * DIM);
                d4[lane & 31] = s4[lane & 31];
            }
        }
        o_cur = o_nxt;
    }
}

extern "C" void kernel_launch(void* const* d_in, const int* in_sizes, int n_in,
                              void* d_out, int out_size, void* d_ws, size_t ws_size,
                              hipStream_t stream) {
    const int*   src  = (const int*)d_in[0];
    const int*   dst  = (const int*)d_in[1];
    const float* prev = (const float*)d_in[2];
    const float* nsrc = (const float*)d_in[3];
    const float* ndst = (const float*)d_in[4];
    const float* Wnig = (const float*)d_in[5];
    const float* bnig = (const float*)d_in[6];
    const float* Wnode = (const float*)d_in[7];
    const float* bnode = (const float*)d_in[8];
    float* out = (float*)d_out;

    const size_t OWNER_B = (size_t)NN * 4;
    const size_t PA_B = 32 * 64 * 8 * 2;     // 32 KB each
    if (ws_size < OWNER_B + 2 * PA_B + 512) return;
    char* ws = (char*)d_ws;
    int*   owner = (int*)ws;
    short* PA = (short*)(ws + OWNER_B);
    short* PQ = (short*)(ws + OWNER_B + PA_B);
    float* cvec = (float*)(ws + OWNER_B + 2 * PA_B);

    hipMemsetAsync(owner, 0xFF, OWNER_B, stream);     // owner[i] = -1
    k_prep<<<NB_PREP, 256, 0, stream>>>(
        src, dst, owner, Wnig, bnig, Wnode, bnode, PA, PQ, cvec);
    k_node<<<GRID_MAIN, BLK_MAIN, 0, stream>>>(
        prev, nsrc, ndst, owner, PA, PQ, cvec, out);
}